// Round 1
// baseline (1203.569 us; speedup 1.0000x reference)
//
#include <hip/hip_runtime.h>
#include <cstdint>
#include <cstddef>

#define DIM 128
#define NG 128
#define NCLS 10
#define SCAN_B 1024
#define PSLICE 8

// ---------------- preprocessing ----------------

__global__ void k_hist(const int* __restrict__ row, int E, int* __restrict__ cnt) {
  int stride = gridDim.x * blockDim.x;
  for (int i = blockIdx.x * blockDim.x + threadIdx.x; i < E; i += stride)
    atomicAdd(&cnt[row[i]], 1);
}

__global__ void k_dis(const int* __restrict__ cnt, float* __restrict__ dis, int N) {
  int i = blockIdx.x * blockDim.x + threadIdx.x;
  if (i < N) {
    float d = (float)(cnt[i] + 1);  // +1 self loop
    dis[i] = 1.0f / sqrtf(d);
  }
}

__global__ void k_scan1(const int* __restrict__ in, int* __restrict__ inc,
                        int* __restrict__ bsum, int N) {
  __shared__ int s[SCAN_B];
  int t = threadIdx.x;
  int gi = blockIdx.x * SCAN_B + t;
  s[t] = (gi < N) ? in[gi] : 0;
  __syncthreads();
  for (int off = 1; off < SCAN_B; off <<= 1) {
    int x = (t >= off) ? s[t - off] : 0;
    __syncthreads();
    s[t] += x;
    __syncthreads();
  }
  if (gi < N) inc[gi] = s[t];
  if (t == SCAN_B - 1) bsum[blockIdx.x] = s[t];
}

__global__ void k_scan2(const int* __restrict__ bsum, int* __restrict__ boff, int nb) {
  if (blockIdx.x == 0 && threadIdx.x == 0) {
    int acc = 0;
    for (int i = 0; i < nb; ++i) { boff[i] = acc; acc += bsum[i]; }
  }
}

__global__ void k_scan3(const int* __restrict__ inc, const int* __restrict__ cnt,
                        const int* __restrict__ boff, int* __restrict__ offs,
                        int N, int E) {
  int i = blockIdx.x * blockDim.x + threadIdx.x;
  if (i < N) offs[i] = inc[i] - cnt[i] + boff[i / SCAN_B];
  if (i == 0) offs[N] = E;
}

__global__ void k_scatter(const int* __restrict__ rw, const int* __restrict__ cl, int E,
                          const float* __restrict__ dis, const int* __restrict__ offs,
                          int* __restrict__ cursor, int* __restrict__ csr_col,
                          float* __restrict__ csr_w) {
  int stride = gridDim.x * blockDim.x;
  for (int i = blockIdx.x * blockDim.x + threadIdx.x; i < E; i += stride) {
    int r = rw[i], c = cl[i];
    int pos = offs[r] + atomicAdd(&cursor[r], 1);
    csr_col[pos] = c;
    csr_w[pos] = dis[c];
  }
}

// ---------------- GEMM: H = X @ W + b  (fp32, W in LDS) ----------------

__global__ __launch_bounds__(256, 2) void k_gemm(
    const float* __restrict__ X, const float* __restrict__ W,
    const float* __restrict__ bias, float* __restrict__ H, int N) {
  __shared__ float Ws[DIM * DIM];  // 64 KiB exactly
  int t = threadIdx.x;
  for (int i = t; i < DIM * DIM; i += 256) Ws[i] = W[i];
  int lane = t & 63, wv = t >> 6;
  float b0 = bias[lane], b1 = bias[lane + 64];
  __syncthreads();
  const int step = gridDim.x * 16;
  for (int r0 = blockIdx.x * 16 + wv * 4; r0 < N; r0 += step) {
    float2 xv0 = *(const float2*)(X + (size_t)(r0 + 0) * DIM + lane * 2);
    float2 xv1 = *(const float2*)(X + (size_t)(r0 + 1) * DIM + lane * 2);
    float2 xv2 = *(const float2*)(X + (size_t)(r0 + 2) * DIM + lane * 2);
    float2 xv3 = *(const float2*)(X + (size_t)(r0 + 3) * DIM + lane * 2);
    float a00 = 0.f, a01 = 0.f, a10 = 0.f, a11 = 0.f;
    float a20 = 0.f, a21 = 0.f, a30 = 0.f, a31 = 0.f;
#pragma unroll 16
    for (int k = 0; k < DIM; ++k) {
      float w0 = Ws[k * DIM + lane];
      float w1 = Ws[k * DIM + lane + 64];
      float x0 = __shfl((k & 1) ? xv0.y : xv0.x, k >> 1);
      float x1 = __shfl((k & 1) ? xv1.y : xv1.x, k >> 1);
      float x2 = __shfl((k & 1) ? xv2.y : xv2.x, k >> 1);
      float x3 = __shfl((k & 1) ? xv3.y : xv3.x, k >> 1);
      a00 = fmaf(x0, w0, a00); a01 = fmaf(x0, w1, a01);
      a10 = fmaf(x1, w0, a10); a11 = fmaf(x1, w1, a11);
      a20 = fmaf(x2, w0, a20); a21 = fmaf(x2, w1, a21);
      a30 = fmaf(x3, w0, a30); a31 = fmaf(x3, w1, a31);
    }
    H[(size_t)(r0 + 0) * DIM + lane] = a00 + b0;
    H[(size_t)(r0 + 0) * DIM + lane + 64] = a01 + b1;
    H[(size_t)(r0 + 1) * DIM + lane] = a10 + b0;
    H[(size_t)(r0 + 1) * DIM + lane + 64] = a11 + b1;
    H[(size_t)(r0 + 2) * DIM + lane] = a20 + b0;
    H[(size_t)(r0 + 2) * DIM + lane + 64] = a21 + b1;
    H[(size_t)(r0 + 3) * DIM + lane] = a30 + b0;
    H[(size_t)(r0 + 3) * DIM + lane + 64] = a31 + b1;
  }
}

// ---------------- aggregation: out[r] = relu(dis[r]*(sum_c dis[c]*H[c] + dis[r]*H[r])) ----------------

__global__ __launch_bounds__(256) void k_agg(
    const float* __restrict__ H, float* __restrict__ out,
    const int* __restrict__ csr_col, const float* __restrict__ csr_w,
    const int* __restrict__ offs, const float* __restrict__ dis, int N) {
  int wid = (int)(((size_t)blockIdx.x * blockDim.x + threadIdx.x) >> 6);
  int lane = threadIdx.x & 63;
  if (wid >= N) return;
  int s = offs[wid], e = offs[wid + 1];
  float dr = dis[wid];
  float2 self = *(const float2*)(H + (size_t)wid * DIM + lane * 2);
  float ax = dr * self.x, ay = dr * self.y;
  for (int i = s; i < e; ++i) {
    int c = csr_col[i];
    float w = csr_w[i];
    float2 h = *(const float2*)(H + (size_t)c * DIM + lane * 2);
    ax = fmaf(w, h.x, ax);
    ay = fmaf(w, h.y, ay);
  }
  float2 o;
  o.x = fmaxf(dr * ax, 0.0f);
  o.y = fmaxf(dr * ay, 0.0f);
  *(float2*)(out + (size_t)wid * DIM + lane * 2) = o;
}

// ---------------- pooling ----------------

__global__ void k_bounds(const int* __restrict__ batch, int N, int G,
                         int* __restrict__ starts) {
  int i = blockIdx.x * blockDim.x + threadIdx.x;
  if (i >= N) return;
  int b = batch[i];
  int pb = (i == 0) ? -1 : batch[i - 1];
  for (int g = pb + 1; g <= b; ++g) starts[g] = i;
  if (i == N - 1) {
    for (int g = b + 1; g <= G; ++g) starts[g] = N;
  }
}

__global__ void k_pool1(const float* __restrict__ A, const int* __restrict__ starts,
                        float* __restrict__ part) {
  int g = blockIdx.x / PSLICE, sl = blockIdx.x % PSLICE;
  int c = threadIdx.x;  // 128
  int s = starts[g], e = starts[g + 1];
  int len = e - s;
  int ns = s + (len * sl) / PSLICE;
  int ne = s + (len * (sl + 1)) / PSLICE;
  float sum = 0.f, mx = -INFINITY;
  for (int n = ns; n < ne; ++n) {
    float v = A[(size_t)n * DIM + c];
    sum += v;
    mx = fmaxf(mx, v);
  }
  part[((size_t)(g * PSLICE + sl) * 2 + 0) * DIM + c] = sum;
  part[((size_t)(g * PSLICE + sl) * 2 + 1) * DIM + c] = mx;
}

__global__ void k_pool2(const float* __restrict__ part, const int* __restrict__ starts,
                        float* __restrict__ GF) {
  int g = blockIdx.x;
  int c = threadIdx.x;  // 128
  float sum = 0.f, mx = -INFINITY;
  for (int sl = 0; sl < PSLICE; ++sl) {
    sum += part[((size_t)(g * PSLICE + sl) * 2 + 0) * DIM + c];
    mx = fmaxf(mx, part[((size_t)(g * PSLICE + sl) * 2 + 1) * DIM + c]);
  }
  int cntg = starts[g + 1] - starts[g];
  GF[(size_t)g * 256 + c] = sum / ((float)cntg + 1e-12f);
  GF[(size_t)g * 256 + 128 + c] = mx;
}

// ---------------- MLP ----------------

__global__ void k_mlp1(const float* __restrict__ GF, const float* __restrict__ Wm1,
                       const float* __restrict__ bm1, float* __restrict__ H1) {
  __shared__ float gs[256];
  int g = blockIdx.x, j = threadIdx.x;  // 128 threads
  gs[j] = GF[(size_t)g * 256 + j];
  gs[j + 128] = GF[(size_t)g * 256 + 128 + j];
  __syncthreads();
  float acc = bm1[j];
#pragma unroll 8
  for (int k = 0; k < 256; ++k) acc = fmaf(gs[k], Wm1[k * DIM + j], acc);
  H1[(size_t)g * DIM + j] = fmaxf(acc, 0.f);
}

__global__ void k_mlp2(const float* __restrict__ H1, const float* __restrict__ Wm2,
                       const float* __restrict__ bm2, float* __restrict__ out) {
  __shared__ float hs[DIM];
  int g = blockIdx.x, j = threadIdx.x;  // 64 threads
  hs[j] = H1[(size_t)g * DIM + j];
  hs[j + 64] = H1[(size_t)g * DIM + j + 64];
  __syncthreads();
  if (j < NCLS) {
    float acc = bm2[j];
#pragma unroll 8
    for (int k = 0; k < DIM; ++k) acc = fmaf(hs[k], Wm2[k * NCLS + j], acc);
    out[(size_t)g * NCLS + j] = acc;
  }
}

// ---------------- host ----------------

static inline size_t al256(size_t x) { return (x + 255) & ~(size_t)255; }

extern "C" void kernel_launch(void* const* d_in, const int* in_sizes, int n_in,
                              void* d_out, int out_size, void* d_ws, size_t ws_size,
                              hipStream_t stream) {
  const float* X = (const float*)d_in[0];
  const int* EI = (const int*)d_in[1];
  const int* batch = (const int*)d_in[2];
  const float* W1 = (const float*)d_in[4];
  const float* b1 = (const float*)d_in[5];
  const float* W2 = (const float*)d_in[6];
  const float* b2 = (const float*)d_in[7];
  const float* W3 = (const float*)d_in[8];
  const float* b3 = (const float*)d_in[9];
  const float* Wm1 = (const float*)d_in[10];
  const float* bm1 = (const float*)d_in[11];
  const float* Wm2 = (const float*)d_in[12];
  const float* bm2 = (const float*)d_in[13];
  float* OUT = (float*)d_out;

  const int N = in_sizes[0] / DIM;
  const int E = in_sizes[1] / 2;
  const int G = NG;
  const int nb = (N + SCAN_B - 1) / SCAN_B;

  const int* EI_row = EI;
  const int* EI_col = EI + E;

  char* p = (char*)d_ws;
  size_t off = 0;
  auto take = [&](size_t bytes) { void* r = p + off; off = al256(off + bytes); return r; };

  int* cnt = (int*)take((size_t)N * 4);
  int* cursor = (int*)take((size_t)N * 4);
  int* inc = (int*)take((size_t)N * 4);
  int* offs = (int*)take((size_t)(N + 1) * 4);
  int* bsum = (int*)take((size_t)nb * 4);
  int* boff = (int*)take((size_t)nb * 4);
  int* starts = (int*)take((size_t)(G + 1) * 4);
  float* dis = (float*)take((size_t)N * 4);
  int* csr_col = (int*)take((size_t)E * 4);
  float* csr_w = (float*)take((size_t)E * 4);
  float* B = (float*)take((size_t)N * DIM * 4);
  float* A = (float*)take((size_t)N * DIM * 4);
  float* part = (float*)take((size_t)G * PSLICE * 2 * DIM * 4);
  float* GF = (float*)take((size_t)G * 256 * 4);
  float* H1 = (float*)take((size_t)G * DIM * 4);
  (void)ws_size; (void)n_in; (void)out_size;

  hipMemsetAsync(cnt, 0, (size_t)N * 4, stream);
  hipMemsetAsync(cursor, 0, (size_t)N * 4, stream);

  // degree + dis
  k_hist<<<1024, 256, 0, stream>>>(EI_row, E, cnt);
  k_dis<<<(N + 255) / 256, 256, 0, stream>>>(cnt, dis, N);
  // exclusive scan -> CSR offsets
  k_scan1<<<nb, SCAN_B, 0, stream>>>(cnt, inc, bsum, N);
  k_scan2<<<1, 1, 0, stream>>>(bsum, boff, nb);
  k_scan3<<<(N + 255) / 256, 256, 0, stream>>>(inc, cnt, boff, offs, N, E);
  // scatter edges into CSR
  k_scatter<<<1024, 256, 0, stream>>>(EI_row, EI_col, E, dis, offs, cursor, csr_col, csr_w);

  const int aggBlocks = (int)(((size_t)N * 64 + 255) / 256);

  // layer 1
  k_gemm<<<512, 256, 0, stream>>>(X, W1, b1, B, N);
  k_agg<<<aggBlocks, 256, 0, stream>>>(B, A, csr_col, csr_w, offs, dis, N);
  // layer 2
  k_gemm<<<512, 256, 0, stream>>>(A, W2, b2, B, N);
  k_agg<<<aggBlocks, 256, 0, stream>>>(B, A, csr_col, csr_w, offs, dis, N);
  // layer 3
  k_gemm<<<512, 256, 0, stream>>>(A, W3, b3, B, N);
  k_agg<<<aggBlocks, 256, 0, stream>>>(B, A, csr_col, csr_w, offs, dis, N);

  // pooling
  k_bounds<<<(N + 255) / 256, 256, 0, stream>>>(batch, N, G, starts);
  k_pool1<<<G * PSLICE, DIM, 0, stream>>>(A, starts, part);
  k_pool2<<<G, DIM, 0, stream>>>(part, starts, GF);

  // MLP head
  k_mlp1<<<G, DIM, 0, stream>>>(GF, Wm1, bm1, H1);
  k_mlp2<<<G, 64, 0, stream>>>(H1, Wm2, bm2, OUT);
}

// Round 2
// 803.769 us; speedup vs baseline: 1.4974x; 1.4974x over previous
//
#include <hip/hip_runtime.h>
#include <cstdint>
#include <cstddef>

#define DIM 128
#define NG 128
#define NCLS 10
#define SCAN_B 1024
#define PSLICE 8

// ---------------- preprocessing ----------------

__global__ void k_hist(const int* __restrict__ row, int E, int* __restrict__ cnt) {
  int stride = gridDim.x * blockDim.x;
  for (int i = blockIdx.x * blockDim.x + threadIdx.x; i < E; i += stride)
    atomicAdd(&cnt[row[i]], 1);
}

__global__ void k_dis(const int* __restrict__ cnt, float* __restrict__ dis, int N) {
  int i = blockIdx.x * blockDim.x + threadIdx.x;
  if (i < N) {
    float d = (float)(cnt[i] + 1);  // +1 self loop
    dis[i] = 1.0f / sqrtf(d);
  }
}

__global__ void k_scan1(const int* __restrict__ in, int* __restrict__ inc,
                        int* __restrict__ bsum, int N) {
  __shared__ int s[SCAN_B];
  int t = threadIdx.x;
  int gi = blockIdx.x * SCAN_B + t;
  s[t] = (gi < N) ? in[gi] : 0;
  __syncthreads();
  for (int off = 1; off < SCAN_B; off <<= 1) {
    int x = (t >= off) ? s[t - off] : 0;
    __syncthreads();
    s[t] += x;
    __syncthreads();
  }
  if (gi < N) inc[gi] = s[t];
  if (t == SCAN_B - 1) bsum[blockIdx.x] = s[t];
}

__global__ void k_scan2(const int* __restrict__ bsum, int* __restrict__ boff, int nb) {
  if (blockIdx.x == 0 && threadIdx.x == 0) {
    int acc = 0;
    for (int i = 0; i < nb; ++i) { boff[i] = acc; acc += bsum[i]; }
  }
}

__global__ void k_scan3(const int* __restrict__ inc, const int* __restrict__ cnt,
                        const int* __restrict__ boff, int* __restrict__ offs,
                        int N, int E) {
  int i = blockIdx.x * blockDim.x + threadIdx.x;
  if (i < N) offs[i] = inc[i] - cnt[i] + boff[i / SCAN_B];
  if (i == 0) offs[N] = E;
}

__global__ void k_scatter(const int* __restrict__ rw, const int* __restrict__ cl, int E,
                          const float* __restrict__ dis, const int* __restrict__ offs,
                          int* __restrict__ cursor, int* __restrict__ csr_col,
                          float* __restrict__ csr_w) {
  int stride = gridDim.x * blockDim.x;
  for (int i = blockIdx.x * blockDim.x + threadIdx.x; i < E; i += stride) {
    int r = rw[i], c = cl[i];
    int pos = offs[r] + atomicAdd(&cursor[r], 1);
    csr_col[pos] = c;
    csr_w[pos] = dis[c];
  }
}

// ---------------- GEMM: H = X @ W + b  (fp32, W in LDS, 4x8 per lane) ----------------
// wave = 4 row-groups x 16 col-lanes; wave covers 16 rows x 128 cols.
// block = 4 waves = 64 rows/tile. X rows held in registers (8 floats/row/lane),
// broadcast via __shfl (source lane constant over 8 consecutive k).

__global__ __launch_bounds__(256, 2) void k_gemm(
    const float* __restrict__ X, const float* __restrict__ W,
    const float* __restrict__ bias, float* __restrict__ H, int N) {
  __shared__ float Ws[DIM * DIM];  // 64 KiB
  int t = threadIdx.x;
  for (int i = t * 4; i < DIM * DIM; i += 1024)
    *(float4*)(Ws + i) = *(const float4*)(W + i);

  int lane = t & 63;
  int wv = t >> 6;          // wave in block (0..3)
  int g = lane >> 4;        // row group in wave (0..3)
  int tx = lane & 15;       // col lane (0..15)
  int colb = tx * 8;
  int lane48 = lane & 48;
  float4 bv0 = *(const float4*)(bias + colb);
  float4 bv1 = *(const float4*)(bias + colb + 4);
  __syncthreads();

  const int ntiles = (N + 63) / 64;
  for (int tile = blockIdx.x; tile < ntiles; tile += gridDim.x) {
    int row0 = tile * 64 + wv * 16 + g * 4;  // this lane's 4 rows
    // load X rows into registers: lane (g,tx) holds cols [tx*8, tx*8+8)
    float xr[4][8];
#pragma unroll
    for (int j = 0; j < 4; ++j) {
      int r = row0 + j;
      if (r < N) {
        *(float4*)&xr[j][0] = *(const float4*)(X + (size_t)r * DIM + colb);
        *(float4*)&xr[j][4] = *(const float4*)(X + (size_t)r * DIM + colb + 4);
      } else {
#pragma unroll
        for (int c = 0; c < 8; ++c) xr[j][c] = 0.f;
      }
    }
    float acc[4][8];
#pragma unroll
    for (int j = 0; j < 4; ++j)
#pragma unroll
      for (int c = 0; c < 8; ++c) acc[j][c] = 0.f;

    for (int k8 = 0; k8 < DIM; k8 += 8) {
      int src = lane48 | (k8 >> 3);  // source lane for this k-octet
#pragma unroll
      for (int c8 = 0; c8 < 8; ++c8) {
        int k = k8 + c8;
        float4 w0 = *(const float4*)(Ws + k * DIM + colb);
        float4 w1 = *(const float4*)(Ws + k * DIM + colb + 4);
#pragma unroll
        for (int j = 0; j < 4; ++j) {
          float x = __shfl(xr[j][c8], src);
          acc[j][0] = fmaf(x, w0.x, acc[j][0]);
          acc[j][1] = fmaf(x, w0.y, acc[j][1]);
          acc[j][2] = fmaf(x, w0.z, acc[j][2]);
          acc[j][3] = fmaf(x, w0.w, acc[j][3]);
          acc[j][4] = fmaf(x, w1.x, acc[j][4]);
          acc[j][5] = fmaf(x, w1.y, acc[j][5]);
          acc[j][6] = fmaf(x, w1.z, acc[j][6]);
          acc[j][7] = fmaf(x, w1.w, acc[j][7]);
        }
      }
    }
#pragma unroll
    for (int j = 0; j < 4; ++j) {
      int r = row0 + j;
      if (r < N) {
        float4 o0, o1;
        o0.x = acc[j][0] + bv0.x; o0.y = acc[j][1] + bv0.y;
        o0.z = acc[j][2] + bv0.z; o0.w = acc[j][3] + bv0.w;
        o1.x = acc[j][4] + bv1.x; o1.y = acc[j][5] + bv1.y;
        o1.z = acc[j][6] + bv1.z; o1.w = acc[j][7] + bv1.w;
        *(float4*)(H + (size_t)r * DIM + colb) = o0;
        *(float4*)(H + (size_t)r * DIM + colb + 4) = o1;
      }
    }
  }
}

// ---------------- aggregation ----------------
// out[r] = relu(dis[r]*(sum_c dis[c]*H[c] + dis[r]*H[r]))
// wave per row; lanes split into two 32-lane halves, each half processes
// alternating neighbors with float4 (16B) loads; combine via shfl_xor(32).

__global__ __launch_bounds__(256) void k_agg(
    const float* __restrict__ H, float* __restrict__ out,
    const int* __restrict__ csr_col, const float* __restrict__ csr_w,
    const int* __restrict__ offs, const float* __restrict__ dis, int N) {
  int wid = (int)(((size_t)blockIdx.x * blockDim.x + threadIdx.x) >> 6);
  int lane = threadIdx.x & 63;
  if (wid >= N) return;
  int half = lane >> 5;
  int q = lane & 31;
  int s = offs[wid], e = offs[wid + 1];
  int cnt = e - s;
  float dr = dis[wid];
  float4 self = *(const float4*)(H + wid * DIM + q * 4);
  float ax = 0.f, ay = 0.f, az = 0.f, aw = 0.f;
  for (int i = half; i < cnt; i += 2) {
    int idx = s + i;
    int c = csr_col[idx];
    float w = csr_w[idx];
    const float* hp = H + c * DIM + q * 4;
    float4 h = *(const float4*)hp;
    ax = fmaf(w, h.x, ax);
    ay = fmaf(w, h.y, ay);
    az = fmaf(w, h.z, az);
    aw = fmaf(w, h.w, aw);
  }
  ax += __shfl_xor(ax, 32);
  ay += __shfl_xor(ay, 32);
  az += __shfl_xor(az, 32);
  aw += __shfl_xor(aw, 32);
  if (lane < 32) {
    float4 o;
    o.x = fmaxf(dr * fmaf(dr, self.x, ax), 0.f);
    o.y = fmaxf(dr * fmaf(dr, self.y, ay), 0.f);
    o.z = fmaxf(dr * fmaf(dr, self.z, az), 0.f);
    o.w = fmaxf(dr * fmaf(dr, self.w, aw), 0.f);
    *(float4*)(out + wid * DIM + q * 4) = o;
  }
}

// ---------------- pooling ----------------

__global__ void k_bounds(const int* __restrict__ batch, int N, int G,
                         int* __restrict__ starts) {
  int i = blockIdx.x * blockDim.x + threadIdx.x;
  if (i >= N) return;
  int b = batch[i];
  int pb = (i == 0) ? -1 : batch[i - 1];
  for (int g = pb + 1; g <= b; ++g) starts[g] = i;
  if (i == N - 1) {
    for (int g = b + 1; g <= G; ++g) starts[g] = N;
  }
}

__global__ void k_pool1(const float* __restrict__ A, const int* __restrict__ starts,
                        float* __restrict__ part) {
  int g = blockIdx.x / PSLICE, sl = blockIdx.x % PSLICE;
  int c = threadIdx.x;  // 128
  int s = starts[g], e = starts[g + 1];
  int len = e - s;
  int ns = s + (len * sl) / PSLICE;
  int ne = s + (len * (sl + 1)) / PSLICE;
  float sum = 0.f, mx = -INFINITY;
  for (int n = ns; n < ne; ++n) {
    float v = A[(size_t)n * DIM + c];
    sum += v;
    mx = fmaxf(mx, v);
  }
  part[((size_t)(g * PSLICE + sl) * 2 + 0) * DIM + c] = sum;
  part[((size_t)(g * PSLICE + sl) * 2 + 1) * DIM + c] = mx;
}

__global__ void k_pool2(const float* __restrict__ part, const int* __restrict__ starts,
                        float* __restrict__ GF) {
  int g = blockIdx.x;
  int c = threadIdx.x;  // 128
  float sum = 0.f, mx = -INFINITY;
  for (int sl = 0; sl < PSLICE; ++sl) {
    sum += part[((size_t)(g * PSLICE + sl) * 2 + 0) * DIM + c];
    mx = fmaxf(mx, part[((size_t)(g * PSLICE + sl) * 2 + 1) * DIM + c]);
  }
  int cntg = starts[g + 1] - starts[g];
  GF[(size_t)g * 256 + c] = sum / ((float)cntg + 1e-12f);
  GF[(size_t)g * 256 + 128 + c] = mx;
}

// ---------------- MLP ----------------

__global__ void k_mlp1(const float* __restrict__ GF, const float* __restrict__ Wm1,
                       const float* __restrict__ bm1, float* __restrict__ H1) {
  __shared__ float gs[256];
  int g = blockIdx.x, j = threadIdx.x;  // 128 threads
  gs[j] = GF[(size_t)g * 256 + j];
  gs[j + 128] = GF[(size_t)g * 256 + 128 + j];
  __syncthreads();
  float acc = bm1[j];
#pragma unroll 8
  for (int k = 0; k < 256; ++k) acc = fmaf(gs[k], Wm1[k * DIM + j], acc);
  H1[(size_t)g * DIM + j] = fmaxf(acc, 0.f);
}

__global__ void k_mlp2(const float* __restrict__ H1, const float* __restrict__ Wm2,
                       const float* __restrict__ bm2, float* __restrict__ out) {
  __shared__ float hs[DIM];
  int g = blockIdx.x, j = threadIdx.x;  // 64 threads
  hs[j] = H1[(size_t)g * DIM + j];
  hs[j + 64] = H1[(size_t)g * DIM + j + 64];
  __syncthreads();
  if (j < NCLS) {
    float acc = bm2[j];
#pragma unroll 8
    for (int k = 0; k < DIM; ++k) acc = fmaf(hs[k], Wm2[k * NCLS + j], acc);
    out[(size_t)g * NCLS + j] = acc;
  }
}

// ---------------- host ----------------

static inline size_t al256(size_t x) { return (x + 255) & ~(size_t)255; }

extern "C" void kernel_launch(void* const* d_in, const int* in_sizes, int n_in,
                              void* d_out, int out_size, void* d_ws, size_t ws_size,
                              hipStream_t stream) {
  const float* X = (const float*)d_in[0];
  const int* EI = (const int*)d_in[1];
  const int* batch = (const int*)d_in[2];
  const float* W1 = (const float*)d_in[4];
  const float* b1 = (const float*)d_in[5];
  const float* W2 = (const float*)d_in[6];
  const float* b2 = (const float*)d_in[7];
  const float* W3 = (const float*)d_in[8];
  const float* b3 = (const float*)d_in[9];
  const float* Wm1 = (const float*)d_in[10];
  const float* bm1 = (const float*)d_in[11];
  const float* Wm2 = (const float*)d_in[12];
  const float* bm2 = (const float*)d_in[13];
  float* OUT = (float*)d_out;

  const int N = in_sizes[0] / DIM;
  const int E = in_sizes[1] / 2;
  const int G = NG;
  const int nb = (N + SCAN_B - 1) / SCAN_B;

  const int* EI_row = EI;
  const int* EI_col = EI + E;

  char* p = (char*)d_ws;
  size_t off = 0;
  auto take = [&](size_t bytes) { void* r = p + off; off = al256(off + bytes); return r; };

  int* cnt = (int*)take((size_t)N * 4);
  int* cursor = (int*)take((size_t)N * 4);
  int* inc = (int*)take((size_t)N * 4);
  int* offs = (int*)take((size_t)(N + 1) * 4);
  int* bsum = (int*)take((size_t)nb * 4);
  int* boff = (int*)take((size_t)nb * 4);
  int* starts = (int*)take((size_t)(G + 1) * 4);
  float* dis = (float*)take((size_t)N * 4);
  int* csr_col = (int*)take((size_t)E * 4);
  float* csr_w = (float*)take((size_t)E * 4);
  float* B = (float*)take((size_t)N * DIM * 4);
  float* A = (float*)take((size_t)N * DIM * 4);
  float* part = (float*)take((size_t)G * PSLICE * 2 * DIM * 4);
  float* GF = (float*)take((size_t)G * 256 * 4);
  float* H1 = (float*)take((size_t)G * DIM * 4);
  (void)ws_size; (void)n_in; (void)out_size;

  hipMemsetAsync(cnt, 0, (size_t)N * 4, stream);
  hipMemsetAsync(cursor, 0, (size_t)N * 4, stream);

  // degree + dis
  k_hist<<<1024, 256, 0, stream>>>(EI_row, E, cnt);
  k_dis<<<(N + 255) / 256, 256, 0, stream>>>(cnt, dis, N);
  // exclusive scan -> CSR offsets
  k_scan1<<<nb, SCAN_B, 0, stream>>>(cnt, inc, bsum, N);
  k_scan2<<<1, 1, 0, stream>>>(bsum, boff, nb);
  k_scan3<<<(N + 255) / 256, 256, 0, stream>>>(inc, cnt, boff, offs, N, E);
  // scatter edges into CSR
  k_scatter<<<1024, 256, 0, stream>>>(EI_row, EI_col, E, dis, offs, cursor, csr_col, csr_w);

  const int aggBlocks = (int)(((size_t)N * 64 + 255) / 256);

  // layer 1
  k_gemm<<<512, 256, 0, stream>>>(X, W1, b1, B, N);
  k_agg<<<aggBlocks, 256, 0, stream>>>(B, A, csr_col, csr_w, offs, dis, N);
  // layer 2
  k_gemm<<<512, 256, 0, stream>>>(A, W2, b2, B, N);
  k_agg<<<aggBlocks, 256, 0, stream>>>(B, A, csr_col, csr_w, offs, dis, N);
  // layer 3
  k_gemm<<<512, 256, 0, stream>>>(A, W3, b3, B, N);
  k_agg<<<aggBlocks, 256, 0, stream>>>(B, A, csr_col, csr_w, offs, dis, N);

  // pooling
  k_bounds<<<(N + 255) / 256, 256, 0, stream>>>(batch, N, G, starts);
  k_pool1<<<G * PSLICE, DIM, 0, stream>>>(A, starts, part);
  k_pool2<<<G, DIM, 0, stream>>>(part, starts, GF);

  // MLP head
  k_mlp1<<<G, DIM, 0, stream>>>(GF, Wm1, bm1, H1);
  k_mlp2<<<G, 64, 0, stream>>>(H1, Wm2, bm2, OUT);
}

// Round 3
// 739.599 us; speedup vs baseline: 1.6273x; 1.0868x over previous
//
#include <hip/hip_runtime.h>
#include <cstdint>
#include <cstddef>

#define DIM 128
#define NG 128
#define NCLS 10
#define SCAN_B 1024
#define PSLICE 8

// ---------------- preprocessing ----------------

__global__ void k_hist(const int* __restrict__ row, int E, int* __restrict__ cnt,
                       int* __restrict__ slot) {
  int stride = gridDim.x * blockDim.x;
  for (int i = blockIdx.x * blockDim.x + threadIdx.x; i < E; i += stride)
    slot[i] = atomicAdd(&cnt[row[i]], 1);
}

__global__ void k_dis(const int* __restrict__ cnt, float* __restrict__ dis, int N) {
  int i = blockIdx.x * blockDim.x + threadIdx.x;
  if (i < N) {
    float d = (float)(cnt[i] + 1);  // +1 self loop
    dis[i] = 1.0f / sqrtf(d);
  }
}

__global__ void k_scan1(const int* __restrict__ in, int* __restrict__ inc,
                        int* __restrict__ bsum, int N) {
  __shared__ int s[SCAN_B];
  int t = threadIdx.x;
  int gi = blockIdx.x * SCAN_B + t;
  s[t] = (gi < N) ? in[gi] : 0;
  __syncthreads();
  for (int off = 1; off < SCAN_B; off <<= 1) {
    int x = (t >= off) ? s[t - off] : 0;
    __syncthreads();
    s[t] += x;
    __syncthreads();
  }
  if (gi < N) inc[gi] = s[t];
  if (t == SCAN_B - 1) bsum[blockIdx.x] = s[t];
}

__global__ void k_scan2(const int* __restrict__ bsum, int* __restrict__ boff, int nb) {
  if (blockIdx.x == 0 && threadIdx.x == 0) {
    int acc = 0;
    for (int i = 0; i < nb; ++i) { boff[i] = acc; acc += bsum[i]; }
  }
}

__global__ void k_scan3(const int* __restrict__ inc, const int* __restrict__ cnt,
                        const int* __restrict__ boff, int* __restrict__ offs,
                        int N, int E) {
  int i = blockIdx.x * blockDim.x + threadIdx.x;
  if (i < N) offs[i] = inc[i] - cnt[i] + boff[i / SCAN_B];
  if (i == 0) offs[N] = E;
}

__global__ void k_scatter(const int* __restrict__ rw, const int* __restrict__ cl, int E,
                          const float* __restrict__ dis, const int* __restrict__ offs,
                          const int* __restrict__ slot, int2* __restrict__ csr) {
  int stride = gridDim.x * blockDim.x;
  for (int i = blockIdx.x * blockDim.x + threadIdx.x; i < E; i += stride) {
    int r = rw[i], c = cl[i];
    int pos = offs[r] + slot[i];
    csr[pos] = make_int2(c, __float_as_int(dis[c]));
  }
}

// ---------------- GEMM: H = X @ W + b  (fp32, W in LDS, 4x8 per lane) ----------------

__global__ __launch_bounds__(256, 2) void k_gemm(
    const float* __restrict__ X, const float* __restrict__ W,
    const float* __restrict__ bias, float* __restrict__ H, int N) {
  __shared__ float Ws[DIM * DIM];  // 64 KiB
  int t = threadIdx.x;
  for (int i = t * 4; i < DIM * DIM; i += 1024)
    *(float4*)(Ws + i) = *(const float4*)(W + i);

  int lane = t & 63;
  int wv = t >> 6;          // wave in block (0..3)
  int g = lane >> 4;        // row group in wave (0..3)
  int tx = lane & 15;       // col lane (0..15)
  int colb = tx * 8;
  int lane48 = lane & 48;
  float4 bv0 = *(const float4*)(bias + colb);
  float4 bv1 = *(const float4*)(bias + colb + 4);
  __syncthreads();

  const int ntiles = (N + 63) / 64;
  for (int tile = blockIdx.x; tile < ntiles; tile += gridDim.x) {
    int row0 = tile * 64 + wv * 16 + g * 4;  // this lane's 4 rows
    float xr[4][8];
#pragma unroll
    for (int j = 0; j < 4; ++j) {
      int r = row0 + j;
      if (r < N) {
        *(float4*)&xr[j][0] = *(const float4*)(X + (size_t)r * DIM + colb);
        *(float4*)&xr[j][4] = *(const float4*)(X + (size_t)r * DIM + colb + 4);
      } else {
#pragma unroll
        for (int c = 0; c < 8; ++c) xr[j][c] = 0.f;
      }
    }
    float acc[4][8];
#pragma unroll
    for (int j = 0; j < 4; ++j)
#pragma unroll
      for (int c = 0; c < 8; ++c) acc[j][c] = 0.f;

    for (int k8 = 0; k8 < DIM; k8 += 8) {
      int src = lane48 | (k8 >> 3);  // source lane for this k-octet
#pragma unroll
      for (int c8 = 0; c8 < 8; ++c8) {
        int k = k8 + c8;
        float4 w0 = *(const float4*)(Ws + k * DIM + colb);
        float4 w1 = *(const float4*)(Ws + k * DIM + colb + 4);
#pragma unroll
        for (int j = 0; j < 4; ++j) {
          float x = __shfl(xr[j][c8], src);
          acc[j][0] = fmaf(x, w0.x, acc[j][0]);
          acc[j][1] = fmaf(x, w0.y, acc[j][1]);
          acc[j][2] = fmaf(x, w0.z, acc[j][2]);
          acc[j][3] = fmaf(x, w0.w, acc[j][3]);
          acc[j][4] = fmaf(x, w1.x, acc[j][4]);
          acc[j][5] = fmaf(x, w1.y, acc[j][5]);
          acc[j][6] = fmaf(x, w1.z, acc[j][6]);
          acc[j][7] = fmaf(x, w1.w, acc[j][7]);
        }
      }
    }
#pragma unroll
    for (int j = 0; j < 4; ++j) {
      int r = row0 + j;
      if (r < N) {
        float4 o0, o1;
        o0.x = acc[j][0] + bv0.x; o0.y = acc[j][1] + bv0.y;
        o0.z = acc[j][2] + bv0.z; o0.w = acc[j][3] + bv0.w;
        o1.x = acc[j][4] + bv1.x; o1.y = acc[j][5] + bv1.y;
        o1.z = acc[j][6] + bv1.z; o1.w = acc[j][7] + bv1.w;
        *(float4*)(H + (size_t)r * DIM + colb) = o0;
        *(float4*)(H + (size_t)r * DIM + colb + 4) = o1;
      }
    }
  }
}

// ---------------- aggregation ----------------
// out[r] = relu(dis[r]*(sum_c dis[c]*H[c] + dis[r]*H[r]))
// wave per row; two 32-lane halves, each unrolled 2x -> 4 row-gathers in flight.

__global__ __launch_bounds__(256) void k_agg(
    const float* __restrict__ H, float* __restrict__ out,
    const int2* __restrict__ csr, const int* __restrict__ offs,
    const float* __restrict__ dis, int N) {
  int wid = (int)(((size_t)blockIdx.x * blockDim.x + threadIdx.x) >> 6);
  int lane = threadIdx.x & 63;
  if (wid >= N) return;
  int half = lane >> 5;
  int q = lane & 31;
  int s = offs[wid], e = offs[wid + 1];
  int cnt = e - s;
  float dr = dis[wid];
  float4 self = *(const float4*)(H + (size_t)wid * DIM + q * 4);
  float a0x = 0.f, a0y = 0.f, a0z = 0.f, a0w = 0.f;
  float a1x = 0.f, a1y = 0.f, a1z = 0.f, a1w = 0.f;
  int i = half;
  for (; i + 2 < cnt; i += 4) {
    int2 e0 = csr[s + i];
    int2 e1 = csr[s + i + 2];
    float4 h0 = *(const float4*)(H + (size_t)e0.x * DIM + q * 4);
    float4 h1 = *(const float4*)(H + (size_t)e1.x * DIM + q * 4);
    float w0 = __int_as_float(e0.y);
    float w1 = __int_as_float(e1.y);
    a0x = fmaf(w0, h0.x, a0x); a0y = fmaf(w0, h0.y, a0y);
    a0z = fmaf(w0, h0.z, a0z); a0w = fmaf(w0, h0.w, a0w);
    a1x = fmaf(w1, h1.x, a1x); a1y = fmaf(w1, h1.y, a1y);
    a1z = fmaf(w1, h1.z, a1z); a1w = fmaf(w1, h1.w, a1w);
  }
  if (i < cnt) {
    int2 e0 = csr[s + i];
    float4 h0 = *(const float4*)(H + (size_t)e0.x * DIM + q * 4);
    float w0 = __int_as_float(e0.y);
    a0x = fmaf(w0, h0.x, a0x); a0y = fmaf(w0, h0.y, a0y);
    a0z = fmaf(w0, h0.z, a0z); a0w = fmaf(w0, h0.w, a0w);
  }
  float ax = a0x + a1x, ay = a0y + a1y, az = a0z + a1z, aw = a0w + a1w;
  ax += __shfl_xor(ax, 32);
  ay += __shfl_xor(ay, 32);
  az += __shfl_xor(az, 32);
  aw += __shfl_xor(aw, 32);
  if (lane < 32) {
    float4 o;
    o.x = fmaxf(dr * fmaf(dr, self.x, ax), 0.f);
    o.y = fmaxf(dr * fmaf(dr, self.y, ay), 0.f);
    o.z = fmaxf(dr * fmaf(dr, self.z, az), 0.f);
    o.w = fmaxf(dr * fmaf(dr, self.w, aw), 0.f);
    *(float4*)(out + (size_t)wid * DIM + q * 4) = o;
  }
}

// ---------------- pooling ----------------

__global__ void k_bounds(const int* __restrict__ batch, int N, int G,
                         int* __restrict__ starts) {
  int i = blockIdx.x * blockDim.x + threadIdx.x;
  if (i >= N) return;
  int b = batch[i];
  int pb = (i == 0) ? -1 : batch[i - 1];
  for (int g = pb + 1; g <= b; ++g) starts[g] = i;
  if (i == N - 1) {
    for (int g = b + 1; g <= G; ++g) starts[g] = N;
  }
}

__global__ void k_pool1(const float* __restrict__ A, const int* __restrict__ starts,
                        float* __restrict__ part) {
  int g = blockIdx.x / PSLICE, sl = blockIdx.x % PSLICE;
  int c = threadIdx.x;  // 128
  int s = starts[g], e = starts[g + 1];
  int len = e - s;
  int ns = s + (len * sl) / PSLICE;
  int ne = s + (len * (sl + 1)) / PSLICE;
  float sum = 0.f, mx = -INFINITY;
  for (int n = ns; n < ne; ++n) {
    float v = A[(size_t)n * DIM + c];
    sum += v;
    mx = fmaxf(mx, v);
  }
  part[((size_t)(g * PSLICE + sl) * 2 + 0) * DIM + c] = sum;
  part[((size_t)(g * PSLICE + sl) * 2 + 1) * DIM + c] = mx;
}

__global__ void k_pool2(const float* __restrict__ part, const int* __restrict__ starts,
                        float* __restrict__ GF) {
  int g = blockIdx.x;
  int c = threadIdx.x;  // 128
  float sum = 0.f, mx = -INFINITY;
  for (int sl = 0; sl < PSLICE; ++sl) {
    sum += part[((size_t)(g * PSLICE + sl) * 2 + 0) * DIM + c];
    mx = fmaxf(mx, part[((size_t)(g * PSLICE + sl) * 2 + 1) * DIM + c]);
  }
  int cntg = starts[g + 1] - starts[g];
  GF[(size_t)g * 256 + c] = sum / ((float)cntg + 1e-12f);
  GF[(size_t)g * 256 + 128 + c] = mx;
}

// ---------------- MLP ----------------

__global__ void k_mlp1(const float* __restrict__ GF, const float* __restrict__ Wm1,
                       const float* __restrict__ bm1, float* __restrict__ H1) {
  __shared__ float gs[256];
  int g = blockIdx.x, j = threadIdx.x;  // 128 threads
  gs[j] = GF[(size_t)g * 256 + j];
  gs[j + 128] = GF[(size_t)g * 256 + 128 + j];
  __syncthreads();
  float acc = bm1[j];
#pragma unroll 8
  for (int k = 0; k < 256; ++k) acc = fmaf(gs[k], Wm1[k * DIM + j], acc);
  H1[(size_t)g * DIM + j] = fmaxf(acc, 0.f);
}

__global__ void k_mlp2(const float* __restrict__ H1, const float* __restrict__ Wm2,
                       const float* __restrict__ bm2, float* __restrict__ out) {
  __shared__ float hs[DIM];
  int g = blockIdx.x, j = threadIdx.x;  // 64 threads
  hs[j] = H1[(size_t)g * DIM + j];
  hs[j + 64] = H1[(size_t)g * DIM + j + 64];
  __syncthreads();
  if (j < NCLS) {
    float acc = bm2[j];
#pragma unroll 8
    for (int k = 0; k < DIM; ++k) acc = fmaf(hs[k], Wm2[k * NCLS + j], acc);
    out[(size_t)g * NCLS + j] = acc;
  }
}

// ---------------- host ----------------

static inline size_t al256(size_t x) { return (x + 255) & ~(size_t)255; }

extern "C" void kernel_launch(void* const* d_in, const int* in_sizes, int n_in,
                              void* d_out, int out_size, void* d_ws, size_t ws_size,
                              hipStream_t stream) {
  const float* X = (const float*)d_in[0];
  const int* EI = (const int*)d_in[1];
  const int* batch = (const int*)d_in[2];
  const float* W1 = (const float*)d_in[4];
  const float* b1 = (const float*)d_in[5];
  const float* W2 = (const float*)d_in[6];
  const float* b2 = (const float*)d_in[7];
  const float* W3 = (const float*)d_in[8];
  const float* b3 = (const float*)d_in[9];
  const float* Wm1 = (const float*)d_in[10];
  const float* bm1 = (const float*)d_in[11];
  const float* Wm2 = (const float*)d_in[12];
  const float* bm2 = (const float*)d_in[13];
  float* OUT = (float*)d_out;

  const int N = in_sizes[0] / DIM;
  const int E = in_sizes[1] / 2;
  const int G = NG;
  const int nb = (N + SCAN_B - 1) / SCAN_B;

  const int* EI_row = EI;
  const int* EI_col = EI + E;

  char* p = (char*)d_ws;
  size_t off = 0;
  auto take = [&](size_t bytes) { void* r = p + off; off = al256(off + bytes); return r; };

  int* cnt = (int*)take((size_t)N * 4);
  int* slot = (int*)take((size_t)E * 4);
  int* inc = (int*)take((size_t)N * 4);
  int* offs = (int*)take((size_t)(N + 1) * 4);
  int* bsum = (int*)take((size_t)nb * 4);
  int* boff = (int*)take((size_t)nb * 4);
  int* starts = (int*)take((size_t)(G + 1) * 4);
  float* dis = (float*)take((size_t)N * 4);
  int2* csr = (int2*)take((size_t)E * 8);
  float* B = (float*)take((size_t)N * DIM * 4);
  float* A = (float*)take((size_t)N * DIM * 4);
  float* part = (float*)take((size_t)G * PSLICE * 2 * DIM * 4);
  float* GF = (float*)take((size_t)G * 256 * 4);
  float* H1 = (float*)take((size_t)G * DIM * 4);
  (void)ws_size; (void)n_in; (void)out_size;

  hipMemsetAsync(cnt, 0, (size_t)N * 4, stream);

  // degree + dis (hist also records per-edge slot within its row)
  k_hist<<<1024, 256, 0, stream>>>(EI_row, E, cnt, slot);
  k_dis<<<(N + 255) / 256, 256, 0, stream>>>(cnt, dis, N);
  // exclusive scan -> CSR offsets
  k_scan1<<<nb, SCAN_B, 0, stream>>>(cnt, inc, bsum, N);
  k_scan2<<<1, 1, 0, stream>>>(bsum, boff, nb);
  k_scan3<<<(N + 255) / 256, 256, 0, stream>>>(inc, cnt, boff, offs, N, E);
  // scatter edges into packed CSR {col, w}
  k_scatter<<<1024, 256, 0, stream>>>(EI_row, EI_col, E, dis, offs, slot, csr);

  const int aggBlocks = (int)(((size_t)N * 64 + 255) / 256);

  // layer 1
  k_gemm<<<512, 256, 0, stream>>>(X, W1, b1, B, N);
  k_agg<<<aggBlocks, 256, 0, stream>>>(B, A, csr, offs, dis, N);
  // layer 2
  k_gemm<<<512, 256, 0, stream>>>(A, W2, b2, B, N);
  k_agg<<<aggBlocks, 256, 0, stream>>>(B, A, csr, offs, dis, N);
  // layer 3
  k_gemm<<<512, 256, 0, stream>>>(A, W3, b3, B, N);
  k_agg<<<aggBlocks, 256, 0, stream>>>(B, A, csr, offs, dis, N);

  // pooling
  k_bounds<<<(N + 255) / 256, 256, 0, stream>>>(batch, N, G, starts);
  k_pool1<<<G * PSLICE, DIM, 0, stream>>>(A, starts, part);
  k_pool2<<<G, DIM, 0, stream>>>(part, starts, GF);

  // MLP head
  k_mlp1<<<G, DIM, 0, stream>>>(GF, Wm1, bm1, H1);
  k_mlp2<<<G, 64, 0, stream>>>(H1, Wm2, bm2, OUT);
}